// Round 12
// baseline (293.297 us; speedup 1.0000x reference)
//
#include <hip/hip_runtime.h>
#include <hip/hip_bf16.h>
#include <math.h>
#include <stdint.h>

typedef __attribute__((ext_vector_type(8))) short short8;
typedef __attribute__((ext_vector_type(4))) float f32x4;

#define BM 256
#define NKT 36
#define A_BYTES (BM * 128)          // 32 KiB per A buffer
#define LDS_TOTAL (2 * A_BYTES)     // 64 KiB total

__device__ __forceinline__ unsigned short f2bf(float f) {
    union { float f; unsigned u; } c; c.f = f;
    unsigned u = c.u;
    unsigned r = u + 0x7fffu + ((u >> 16) & 1u);
    return (unsigned short)(r >> 16);
}

__device__ __forceinline__ float gelu_exact(float x) {
    return 0.5f * x * (1.0f + erff(x * 0.7071067811865475f));
}

// swizzled byte offset for 16B unit u of a 64-bf16 (128B) LDS row
__device__ __forceinline__ int swz(int row, int u) {
    return row * 128 + ((u ^ (row & 7)) << 4);
}

// Frag-major weight image (verified R7): 16B unit
// U = kt*2048 + wc*512 + i*64 + lane, i = kh*4 + n.
// Unit holds W[o][k0..k0+8) with o = wc*64 + n*16 + (lane&15),
// k0 = kt*64 + (kh*4 + (lane>>4))*8.
__global__ void kan_prep_w(const float* __restrict__ bw, const float* __restrict__ sw,
                           unsigned short* __restrict__ Wf) {
    int U = blockIdx.x * 256 + threadIdx.x;   // 36*2048 units
    if (U >= NKT * 2048) return;
    int kt = U >> 11, rem = U & 2047;
    int wcq = rem >> 9, rem2 = rem & 511;
    int i = rem2 >> 6;                 // kh*4 + n
    int lane = rem2 & 63;
    int o = wcq * 64 + (i & 3) * 16 + (lane & 15);
    int k0 = kt * 64 + ((i >> 2) * 4 + (lane >> 4)) * 8;
    unsigned short pk[8];
#pragma unroll
    for (int e = 0; e < 8; ++e) {
        int kk = k0 + e;
        float v = (kk < 256) ? bw[o * 256 + kk] : sw[o * 2048 + (kk - 256)];
        pk[e] = f2bf(v);
    }
    *(short8*)(Wf + (size_t)U * 8) = *(short8*)pk;
}

// spline: 16B row image (8 bf16 slots, 4 nonzero) via funnel shift (verified R2)
__device__ __forceinline__ short8 spline_row(float xv) {
    float xi = (xv + 2.2f) * 2.5f;
    float fi = floorf(xi);
    float tt = xi - fi;
    float s1 = 1.0f - tt;
    float t2 = tt * tt, t3 = t2 * tt;
    float w0 = s1 * s1 * s1 * (1.0f / 6.0f);
    float w1 = 0.5f * t3 - t2 + (2.0f / 3.0f);
    float w2 = -0.5f * t3 + 0.5f * t2 + 0.5f * tt + (1.0f / 6.0f);
    float w3 = t3 * (1.0f / 6.0f);
    uint64_t Wp = (uint64_t)f2bf(w0) | ((uint64_t)f2bf(w1) << 16)
                | ((uint64_t)f2bf(w2) << 32) | ((uint64_t)f2bf(w3) << 48);
    int b = 16 * ((int)fi - 3);
    uint64_t L = (b >= 0 && b < 64) ? (Wp << b)
               : ((b < 0 && b > -64) ? (Wp >> (-b)) : 0ull);
    uint64_t H = (b >= 64 && b < 128) ? (Wp << (b - 64))
               : ((b > 0 && b < 64) ? (Wp >> (64 - b)) : 0ull);
    union { uint64_t q[2]; short8 v; } rr;
    rr.q[0] = L; rr.q[1] = H;
    return rr.v;
}

__global__ __launch_bounds__(512)
__attribute__((amdgpu_waves_per_eu(2, 2)))   // safe (R7-verified); NEVER force >=4 (R8-R10 corruption)
void kan_fused(
    const float* __restrict__ X, const unsigned short* __restrict__ Wf,
    const float* __restrict__ gamma, const float* __restrict__ beta,
    const float* __restrict__ prelu_a, float* __restrict__ OUT)
{
    extern __shared__ __align__(16) unsigned char lds[];   // [A0 32K][A1 32K]

    const int t = threadIdx.x;
    const int row0 = blockIdx.x * BM;
    const int wid = t >> 6, lane = t & 63;
    const int wr = wid >> 2, wc = wid & 3;      // 2 x 4 waves; wave tile 128x64
    const int lcol = lane & 15, q = lane >> 4;
    const int srow = t >> 3, scol = t & 7;      // staging: 4 reps x 64 rows

    f32x4 acc[8][4];
#pragma unroll
    for (int m = 0; m < 8; ++m)
#pragma unroll
        for (int n = 0; n < 4; ++n) acc[m][n] = (f32x4){0.f, 0.f, 0.f, 0.f};

    const unsigned short* wlane = Wf + ((size_t)wc * 512 + lane) * 8;

    short8 wv[8];
    // ---- prologue: W(0) -> wv; A tile 0 (gelu) -> buffer 0 ----
#pragma unroll
    for (int i = 0; i < 8; ++i)
        wv[i] = *(const short8*)(wlane + i * 512);
#pragma unroll
    for (int rep = 0; rep < 4; ++rep) {
        const float* xp = X + (size_t)(row0 + srow + rep * 64) * 256 + scol * 8;
        float4 v0 = *(const float4*)xp;
        float4 v1 = *(const float4*)(xp + 4);
        float vv[8] = {v0.x, v0.y, v0.z, v0.w, v1.x, v1.y, v1.z, v1.w};
        unsigned short pk[8];
#pragma unroll
        for (int j = 0; j < 8; ++j) pk[j] = f2bf(gelu_exact(vv[j]));
        *(short8*)(lds + swz(srow + rep * 64, scol)) = *(short8*)pk;
    }
    asm volatile("s_waitcnt lgkmcnt(0)\n\ts_barrier" ::: "memory");

    // body: consumes xsC (x for tile kt+1, loaded last iteration),
    //       preloads xsN (x for tile kt+2, consumed next iteration)
    auto body = [&](int kt, float (&xsC)[4], float (&xsN)[4]) {
        unsigned char* A_cur = lds + (kt & 1) * A_BYTES;
        unsigned char* A_nxt = lds + ((kt + 1) & 1) * A_BYTES;
        const bool has_next = (kt + 1 < NKT);
        const bool nxt_gelu = (kt + 1 < 4);

        // ---- 1a. distance-2 spline x prefetch (tile kt+2) ----
        if (kt + 2 < NKT && kt + 2 >= 4) {
            const int ibase = (kt + 2 - 4) * 8;
#pragma unroll
            for (int rep = 0; rep < 4; ++rep)
                xsN[rep] = X[(size_t)(row0 + srow + rep * 64) * 256 + ibase + scol];
        }
        // ---- 1b. gelu x prefetch for tile kt+1 (cover = phase 2) ----
        float xg[32];
        if (has_next && nxt_gelu) {
#pragma unroll
            for (int rep = 0; rep < 4; ++rep) {
                const float* xp = X + (size_t)(row0 + srow + rep * 64) * 256
                                + (kt + 1) * 64 + scol * 8;
                float4 v0 = *(const float4*)xp;
                float4 v1 = *(const float4*)(xp + 4);
                xg[rep * 8 + 0] = v0.x; xg[rep * 8 + 1] = v0.y;
                xg[rep * 8 + 2] = v0.z; xg[rep * 8 + 3] = v0.w;
                xg[rep * 8 + 4] = v1.x; xg[rep * 8 + 5] = v1.y;
                xg[rep * 8 + 6] = v1.z; xg[rep * 8 + 7] = v1.w;
            }
        }

        // ---- 2. A frag reads + MFMA (wv loaded in previous iteration) ----
#pragma unroll
        for (int kh = 0; kh < 2; ++kh) {
            short8 af[8];
#pragma unroll
            for (int m = 0; m < 8; ++m)
                af[m] = *(const short8*)(A_cur + swz(wr * 128 + m * 16 + lcol, kh * 4 + q));
#pragma unroll
            for (int m = 0; m < 8; ++m)
#pragma unroll
                for (int n = 0; n < 4; ++n)
                    acc[m][n] = __builtin_amdgcn_mfma_f32_16x16x32_bf16(
                        af[m], wv[kh * 4 + n], acc[m][n], 0, 0, 0);
        }

        // ---- 3. W(kt+1) -> wv (after last use), then A staging for kt+1 ----
        if (has_next) {
            const unsigned short* wsrc = wlane + (size_t)(kt + 1) * 2048 * 8;
#pragma unroll
            for (int i = 0; i < 8; ++i)
                wv[i] = *(const short8*)(wsrc + i * 512);

            if (nxt_gelu) {
#pragma unroll
                for (int rep = 0; rep < 4; ++rep) {
                    unsigned short pk[8];
#pragma unroll
                    for (int j = 0; j < 8; ++j) pk[j] = f2bf(gelu_exact(xg[rep * 8 + j]));
                    *(short8*)(A_nxt + swz(srow + rep * 64, scol)) = *(short8*)pk;
                }
            } else {
#pragma unroll
                for (int rep = 0; rep < 4; ++rep)
                    *(short8*)(A_nxt + swz(srow + rep * 64, scol)) = spline_row(xsC[rep]);
            }
        }
        // LDS-only barrier: keeps x/W reg-loads in flight (no vmcnt drain)
        asm volatile("s_waitcnt lgkmcnt(0)\n\ts_barrier" ::: "memory");
    };

    float xsA[4], xsB[4];
    for (int kp = 0; kp < NKT; kp += 2) {
        body(kp,     xsA, xsB);
        body(kp + 1, xsB, xsA);
    }

    // ---- fused LayerNorm + PReLU epilogue (verified R7) ----
    float* stats = (float*)lds;   // [256][8]: 4 col-partial sums, 4 col-partial sumsq
#pragma unroll
    for (int m = 0; m < 8; ++m) {
#pragma unroll
        for (int r = 0; r < 4; ++r) {
            float s = 0.f, s2 = 0.f;
#pragma unroll
            for (int n = 0; n < 4; ++n) { float v = acc[m][n][r]; s += v; s2 += v * v; }
#pragma unroll
            for (int msk = 1; msk < 16; msk <<= 1) {
                s  += __shfl_xor(s,  msk, 64);
                s2 += __shfl_xor(s2, msk, 64);
            }
            if ((lane & 15) == ((m * 4 + r) & 15)) {
                int row = wr * 128 + m * 16 + q * 4 + r;
                stats[row * 8 + wc]     = s;
                stats[row * 8 + 4 + wc] = s2;
            }
        }
    }
    __syncthreads();

    const float apr = prelu_a[0];
    float gv[4], bv[4];
#pragma unroll
    for (int n = 0; n < 4; ++n) {
        int col = wc * 64 + n * 16 + lcol;
        gv[n] = gamma[col]; bv[n] = beta[col];
    }
#pragma unroll
    for (int m = 0; m < 8; ++m) {
#pragma unroll
        for (int r = 0; r < 4; ++r) {
            int row = wr * 128 + m * 16 + q * 4 + r;
            f32x4 sv = *(const f32x4*)(stats + row * 8);
            f32x4 qv = *(const f32x4*)(stats + row * 8 + 4);
            float mu  = (sv[0] + sv[1] + sv[2] + sv[3]) * (1.0f / 256.0f);
            float ex2 = (qv[0] + qv[1] + qv[2] + qv[3]) * (1.0f / 256.0f);
            float rs = rsqrtf(ex2 - mu * mu + 1e-5f);
            float* op = OUT + (size_t)(row0 + row) * 256;
#pragma unroll
            for (int n = 0; n < 4; ++n) {
                int col = wc * 64 + n * 16 + lcol;
                float y = (acc[m][n][r] - mu) * rs * gv[n] + bv[n];
                op[col] = (y >= 0.f) ? y : apr * y;
            }
        }
    }
}

extern "C" void kernel_launch(void* const* d_in, const int* in_sizes, int n_in,
                              void* d_out, int out_size, void* d_ws, size_t ws_size,
                              hipStream_t stream) {
    const float* x  = (const float*)d_in[0];
    // d_in[1] = grid knots (uniform linspace; constants folded into closed form)
    const float* bw = (const float*)d_in[2];
    const float* sw = (const float*)d_in[3];
    const float* g  = (const float*)d_in[4];
    const float* be = (const float*)d_in[5];
    const float* pa = (const float*)d_in[6];
    float* out = (float*)d_out;
    unsigned short* Wf = (unsigned short*)d_ws;   // 36*2048*16B frag-major

    hipFuncSetAttribute((const void*)kan_fused,
                        hipFuncAttributeMaxDynamicSharedMemorySize, LDS_TOTAL);

    const int Nrows = in_sizes[0] / 256;
    kan_prep_w<<<(NKT * 2048 + 255) / 256, 256, 0, stream>>>(bw, sw, Wf);
    kan_fused<<<Nrows / BM, 512, LDS_TOTAL, stream>>>(x, Wf, g, be, pa, out);
}

// Round 13
// 202.065 us; speedup vs baseline: 1.4515x; 1.4515x over previous
//
#include <hip/hip_runtime.h>
#include <hip/hip_bf16.h>
#include <math.h>
#include <stdint.h>

typedef __attribute__((ext_vector_type(8))) short short8;
typedef __attribute__((ext_vector_type(4))) float f32x4;

#define BM 256
#define NKT 36
#define A_BYTES (BM * 128)          // 32 KiB per A buffer
#define LDS_TOTAL (2 * A_BYTES)     // 64 KiB total

__device__ __forceinline__ unsigned short f2bf(float f) {
    union { float f; unsigned u; } c; c.f = f;
    unsigned u = c.u;
    unsigned r = u + 0x7fffu + ((u >> 16) & 1u);
    return (unsigned short)(r >> 16);
}

__device__ __forceinline__ float gelu_exact(float x) {
    return 0.5f * x * (1.0f + erff(x * 0.7071067811865475f));
}

// swizzled byte offset for 16B unit u of a 64-bf16 (128B) LDS row
__device__ __forceinline__ int swz(int row, int u) {
    return row * 128 + ((u ^ (row & 7)) << 4);
}

// Frag-major weight image (verified R7): 16B unit
// U = kt*2048 + wc*512 + i*64 + lane, i = kh*4 + n.
// Unit holds W[o][k0..k0+8) with o = wc*64 + n*16 + (lane&15),
// k0 = kt*64 + (kh*4 + (lane>>4))*8.
__global__ void kan_prep_w(const float* __restrict__ bw, const float* __restrict__ sw,
                           unsigned short* __restrict__ Wf) {
    int U = blockIdx.x * 256 + threadIdx.x;   // 36*2048 units
    if (U >= NKT * 2048) return;
    int kt = U >> 11, rem = U & 2047;
    int wcq = rem >> 9, rem2 = rem & 511;
    int i = rem2 >> 6;                 // kh*4 + n
    int lane = rem2 & 63;
    int o = wcq * 64 + (i & 3) * 16 + (lane & 15);
    int k0 = kt * 64 + ((i >> 2) * 4 + (lane >> 4)) * 8;
    unsigned short pk[8];
#pragma unroll
    for (int e = 0; e < 8; ++e) {
        int kk = k0 + e;
        float v = (kk < 256) ? bw[o * 256 + kk] : sw[o * 2048 + (kk - 256)];
        pk[e] = f2bf(v);
    }
    *(short8*)(Wf + (size_t)U * 8) = *(short8*)pk;
}

// spline: 16B row image (8 bf16 slots, 4 nonzero) via funnel shift (verified R2)
__device__ __forceinline__ short8 spline_row(float xv) {
    float xi = (xv + 2.2f) * 2.5f;
    float fi = floorf(xi);
    float tt = xi - fi;
    float s1 = 1.0f - tt;
    float t2 = tt * tt, t3 = t2 * tt;
    float w0 = s1 * s1 * s1 * (1.0f / 6.0f);
    float w1 = 0.5f * t3 - t2 + (2.0f / 3.0f);
    float w2 = -0.5f * t3 + 0.5f * t2 + 0.5f * tt + (1.0f / 6.0f);
    float w3 = t3 * (1.0f / 6.0f);
    uint64_t Wp = (uint64_t)f2bf(w0) | ((uint64_t)f2bf(w1) << 16)
                | ((uint64_t)f2bf(w2) << 32) | ((uint64_t)f2bf(w3) << 48);
    int b = 16 * ((int)fi - 3);
    uint64_t L = (b >= 0 && b < 64) ? (Wp << b)
               : ((b < 0 && b > -64) ? (Wp >> (-b)) : 0ull);
    uint64_t H = (b >= 64 && b < 128) ? (Wp << (b - 64))
               : ((b > 0 && b < 64) ? (Wp >> (64 - b)) : 0ull);
    union { uint64_t q[2]; short8 v; } rr;
    rr.q[0] = L; rr.q[1] = H;
    return rr.v;
}

__global__ __launch_bounds__(1024)   // 16 waves = 4/SIMD naturally; NO occupancy pin
void kan_fused(
    const float* __restrict__ X, const unsigned short* __restrict__ Wf,
    const float* __restrict__ gamma, const float* __restrict__ beta,
    const float* __restrict__ prelu_a, float* __restrict__ OUT)
{
    extern __shared__ __align__(16) unsigned char lds[];   // [A0 32K][A1 32K]

    const int t = threadIdx.x;
    const int row0 = blockIdx.x * BM;
    const int wid = t >> 6, lane = t & 63;
    const int wr = wid >> 2, wc = wid & 3;      // 4 x 4 waves; wave tile 64x64
    const int lcol = lane & 15, q = lane >> 4;
    const int srow = t >> 2, sil = (t & 3) << 1;  // staging: 1 row, 2 units/thread

    f32x4 acc[4][4];
#pragma unroll
    for (int m = 0; m < 4; ++m)
#pragma unroll
        for (int n = 0; n < 4; ++n) acc[m][n] = (f32x4){0.f, 0.f, 0.f, 0.f};

    const unsigned short* wlane = Wf + ((size_t)wc * 512 + lane) * 8;

    short8 wv[8];
    // ---- prologue: W(0) -> wv; A tile 0 (gelu) -> buffer 0 ----
#pragma unroll
    for (int i = 0; i < 8; ++i)
        wv[i] = *(const short8*)(wlane + i * 512);
#pragma unroll
    for (int rep = 0; rep < 2; ++rep) {
        const float* xp = X + (size_t)(row0 + srow) * 256 + (sil + rep) * 8;
        float4 v0 = *(const float4*)xp;
        float4 v1 = *(const float4*)(xp + 4);
        float vv[8] = {v0.x, v0.y, v0.z, v0.w, v1.x, v1.y, v1.z, v1.w};
        unsigned short pk[8];
#pragma unroll
        for (int j = 0; j < 8; ++j) pk[j] = f2bf(gelu_exact(vv[j]));
        *(short8*)(lds + swz(srow, sil + rep)) = *(short8*)pk;
    }
    asm volatile("s_waitcnt lgkmcnt(0)\n\ts_barrier" ::: "memory");

    for (int kt = 0; kt < NKT; ++kt) {
        unsigned char* A_cur = lds + (kt & 1) * A_BYTES;
        unsigned char* A_nxt = lds + ((kt + 1) & 1) * A_BYTES;
        const bool has_next = (kt + 1 < NKT);
        const bool nxt_gelu = (kt + 1 < 4);

        // ---- 1. spline x prefetch for next tile (2 consecutive floats) ----
        float xs[2];
        if (has_next && !nxt_gelu) {
            const int ibase = (kt + 1 - 4) * 8;
#pragma unroll
            for (int rep = 0; rep < 2; ++rep)
                xs[rep] = X[(size_t)(row0 + srow) * 256 + ibase + sil + rep];
        }

        // ---- 2. A frag reads + MFMA (wv loaded in previous iteration) ----
#pragma unroll
        for (int kh = 0; kh < 2; ++kh) {
            short8 af[4];
#pragma unroll
            for (int m = 0; m < 4; ++m)
                af[m] = *(const short8*)(A_cur + swz(wr * 64 + m * 16 + lcol, kh * 4 + q));
#pragma unroll
            for (int m = 0; m < 4; ++m)
#pragma unroll
                for (int n = 0; n < 4; ++n)
                    acc[m][n] = __builtin_amdgcn_mfma_f32_16x16x32_bf16(
                        af[m], wv[kh * 4 + n], acc[m][n], 0, 0, 0);
        }

        // ---- 3. W(kt+1) -> wv (after last use), then A staging for kt+1 ----
        if (has_next) {
            const unsigned short* wsrc = wlane + (size_t)(kt + 1) * 2048 * 8;
#pragma unroll
            for (int i = 0; i < 8; ++i)
                wv[i] = *(const short8*)(wsrc + i * 512);

            if (nxt_gelu) {
#pragma unroll
                for (int rep = 0; rep < 2; ++rep) {
                    const float* xp = X + (size_t)(row0 + srow) * 256
                                    + (kt + 1) * 64 + (sil + rep) * 8;
                    float4 v0 = *(const float4*)xp;
                    float4 v1 = *(const float4*)(xp + 4);
                    float vv[8] = {v0.x, v0.y, v0.z, v0.w, v1.x, v1.y, v1.z, v1.w};
                    unsigned short pk[8];
#pragma unroll
                    for (int j = 0; j < 8; ++j) pk[j] = f2bf(gelu_exact(vv[j]));
                    *(short8*)(A_nxt + swz(srow, sil + rep)) = *(short8*)pk;
                }
            } else {
#pragma unroll
                for (int rep = 0; rep < 2; ++rep)
                    *(short8*)(A_nxt + swz(srow, sil + rep)) = spline_row(xs[rep]);
            }
        }
        // LDS-only barrier (R7-verified): W/x reg-loads stay in flight
        asm volatile("s_waitcnt lgkmcnt(0)\n\ts_barrier" ::: "memory");
    }

    // ---- fused LayerNorm + PReLU epilogue ----
    float* stats = (float*)lds;   // [256][8]: 4 col-partial sums, 4 col-partial sumsq
#pragma unroll
    for (int m = 0; m < 4; ++m) {
#pragma unroll
        for (int r = 0; r < 4; ++r) {
            float s = 0.f, s2 = 0.f;
#pragma unroll
            for (int n = 0; n < 4; ++n) { float v = acc[m][n][r]; s += v; s2 += v * v; }
#pragma unroll
            for (int msk = 1; msk < 16; msk <<= 1) {
                s  += __shfl_xor(s,  msk, 64);
                s2 += __shfl_xor(s2, msk, 64);
            }
            if ((lane & 15) == (m * 4 + r)) {
                int row = wr * 64 + m * 16 + q * 4 + r;
                stats[row * 8 + wc]     = s;
                stats[row * 8 + 4 + wc] = s2;
            }
        }
    }
    __syncthreads();

    const float apr = prelu_a[0];
    float gv[4], bv[4];
#pragma unroll
    for (int n = 0; n < 4; ++n) {
        int col = wc * 64 + n * 16 + lcol;
        gv[n] = gamma[col]; bv[n] = beta[col];
    }
#pragma unroll
    for (int m = 0; m < 4; ++m) {
#pragma unroll
        for (int r = 0; r < 4; ++r) {
            int row = wr * 64 + m * 16 + q * 4 + r;
            f32x4 sv = *(const f32x4*)(stats + row * 8);
            f32x4 qv = *(const f32x4*)(stats + row * 8 + 4);
            float mu  = (sv[0] + sv[1] + sv[2] + sv[3]) * (1.0f / 256.0f);
            float ex2 = (qv[0] + qv[1] + qv[2] + qv[3]) * (1.0f / 256.0f);
            float rs = rsqrtf(ex2 - mu * mu + 1e-5f);
            float* op = OUT + (size_t)(row0 + row) * 256;
#pragma unroll
            for (int n = 0; n < 4; ++n) {
                int col = wc * 64 + n * 16 + lcol;
                float y = (acc[m][n][r] - mu) * rs * gv[n] + bv[n];
                op[col] = (y >= 0.f) ? y : apr * y;
            }
        }
    }
}

extern "C" void kernel_launch(void* const* d_in, const int* in_sizes, int n_in,
                              void* d_out, int out_size, void* d_ws, size_t ws_size,
                              hipStream_t stream) {
    const float* x  = (const float*)d_in[0];
    // d_in[1] = grid knots (uniform linspace; constants folded into closed form)
    const float* bw = (const float*)d_in[2];
    const float* sw = (const float*)d_in[3];
    const float* g  = (const float*)d_in[4];
    const float* be = (const float*)d_in[5];
    const float* pa = (const float*)d_in[6];
    float* out = (float*)d_out;
    unsigned short* Wf = (unsigned short*)d_ws;   // 36*2048*16B frag-major

    hipFuncSetAttribute((const void*)kan_fused,
                        hipFuncAttributeMaxDynamicSharedMemorySize, LDS_TOTAL);

    const int Nrows = in_sizes[0] / 256;
    kan_prep_w<<<(NKT * 2048 + 255) / 256, 256, 0, stream>>>(bw, sw, Wf);
    kan_fused<<<Nrows / BM, 1024, LDS_TOTAL, stream>>>(x, Wf, g, be, pa, out);
}

// Round 14
// 126.490 us; speedup vs baseline: 2.3187x; 1.5975x over previous
//
#include <hip/hip_runtime.h>
#include <hip/hip_bf16.h>
#include <math.h>
#include <stdint.h>

typedef __attribute__((ext_vector_type(8))) short short8;
typedef __attribute__((ext_vector_type(4))) float f32x4;

#define BM 256
#define NKT 36
#define A_BYTES (BM * 128)          // 32 KiB per A buffer
#define LDS_TOTAL (4 * A_BYTES)     // 128 KiB: 4-buffer A ring

// native bf16 convert (RNE) — lets compiler emit v_cvt_pk_bf16_f32 for pairs
__device__ __forceinline__ unsigned short f2bf(float f) {
    __bf16 h = (__bf16)f;
    return __builtin_bit_cast(unsigned short, h);
}

__device__ __forceinline__ float gelu_exact(float x) {
    return 0.5f * x * (1.0f + erff(x * 0.7071067811865475f));
}

// swizzled byte offset for 16B unit u of a 64-bf16 (128B) LDS row
__device__ __forceinline__ int swz(int row, int u) {
    return row * 128 + ((u ^ (row & 7)) << 4);
}

// Frag-major weight image (verified R7): 16B unit
// U = kt*2048 + wc*512 + i*64 + lane, i = kh*4 + n.
// Unit holds W[o][k0..k0+8) with o = wc*64 + n*16 + (lane&15),
// k0 = kt*64 + (kh*4 + (lane>>4))*8.
__global__ void kan_prep_w(const float* __restrict__ bw, const float* __restrict__ sw,
                           unsigned short* __restrict__ Wf) {
    int U = blockIdx.x * 256 + threadIdx.x;   // 36*2048 units
    if (U >= NKT * 2048) return;
    int kt = U >> 11, rem = U & 2047;
    int wcq = rem >> 9, rem2 = rem & 511;
    int i = rem2 >> 6;                 // kh*4 + n
    int lane = rem2 & 63;
    int o = wcq * 64 + (i & 3) * 16 + (lane & 15);
    int k0 = kt * 64 + ((i >> 2) * 4 + (lane >> 4)) * 8;
    unsigned short pk[8];
#pragma unroll
    for (int e = 0; e < 8; ++e) {
        int kk = k0 + e;
        float v = (kk < 256) ? bw[o * 256 + kk] : sw[o * 2048 + (kk - 256)];
        pk[e] = f2bf(v);
    }
    *(short8*)(Wf + (size_t)U * 8) = *(short8*)pk;
}

// spline: 16B row image (8 bf16 slots, 4 nonzero) via funnel shift (verified R2)
__device__ __forceinline__ short8 spline_row(float xv) {
    float xi = (xv + 2.2f) * 2.5f;
    float fi = floorf(xi);
    float tt = xi - fi;
    float s1 = 1.0f - tt;
    float t2 = tt * tt, t3 = t2 * tt;
    float w0 = s1 * s1 * s1 * (1.0f / 6.0f);
    float w1 = 0.5f * t3 - t2 + (2.0f / 3.0f);
    float w2 = -0.5f * t3 + 0.5f * t2 + 0.5f * tt + (1.0f / 6.0f);
    float w3 = t3 * (1.0f / 6.0f);
    uint64_t Wp = (uint64_t)f2bf(w0) | ((uint64_t)f2bf(w1) << 16)
                | ((uint64_t)f2bf(w2) << 32) | ((uint64_t)f2bf(w3) << 48);
    int b = 16 * ((int)fi - 3);
    uint64_t L = (b >= 0 && b < 64) ? (Wp << b)
               : ((b < 0 && b > -64) ? (Wp >> (-b)) : 0ull);
    uint64_t H = (b >= 64 && b < 128) ? (Wp << (b - 64))
               : ((b > 0 && b < 64) ? (Wp >> (64 - b)) : 0ull);
    union { uint64_t q[2]; short8 v; } rr;
    rr.q[0] = L; rr.q[1] = H;
    return rr.v;
}

__global__ __launch_bounds__(512)   // 8 waves = 2/SIMD; no occupancy pin (R8-R10 rule)
void kan_fused(
    const float* __restrict__ X, const unsigned short* __restrict__ Wf,
    const float* __restrict__ gamma, const float* __restrict__ beta,
    const float* __restrict__ prelu_a, float* __restrict__ OUT)
{
    extern __shared__ __align__(16) unsigned char lds[];   // 4 x 32K A ring

    const int t = threadIdx.x;
    const int row0 = blockIdx.x * BM;
    const int wid = t >> 6, lane = t & 63;
    const int wr = wid >> 2, wc = wid & 3;      // 2 x 4 waves; wave tile 128x64
    const int lcol = lane & 15, q = lane >> 4;
    const int srow = t >> 3, scol = t & 7;      // staging: 4 reps x 64 rows

    f32x4 acc[8][4];
#pragma unroll
    for (int m = 0; m < 8; ++m)
#pragma unroll
        for (int n = 0; n < 4; ++n) acc[m][n] = (f32x4){0.f, 0.f, 0.f, 0.f};

    const unsigned short* wlane = Wf + ((size_t)wc * 512 + lane) * 8;
    short8 wv[8];

    auto w_load = [&](int kt) {
        const unsigned short* wsrc = wlane + (size_t)kt * 2048 * 8;
#pragma unroll
        for (int i = 0; i < 8; ++i)
            wv[i] = *(const short8*)(wsrc + i * 512);
    };
    auto gelu_stage = [&](int kt, unsigned char* D) {
#pragma unroll
        for (int rep = 0; rep < 4; ++rep) {
            const float* xp = X + (size_t)(row0 + srow + rep * 64) * 256 + kt * 64 + scol * 8;
            float4 v0 = *(const float4*)xp;
            float4 v1 = *(const float4*)(xp + 4);
            float vv[8] = {v0.x, v0.y, v0.z, v0.w, v1.x, v1.y, v1.z, v1.w};
            unsigned short pk[8];
#pragma unroll
            for (int jj = 0; jj < 8; ++jj) pk[jj] = f2bf(gelu_exact(vv[jj]));
            *(short8*)(D + swz(srow + rep * 64, scol)) = *(short8*)pk;
        }
    };
    auto spline_stage = [&](float (&xs)[4], unsigned char* D) {
#pragma unroll
        for (int rep = 0; rep < 4; ++rep)
            *(short8*)(D + swz(srow + rep * 64, scol)) = spline_row(xs[rep]);
    };
    auto mfma_tile = [&](unsigned char* B) {
#pragma unroll
        for (int kh = 0; kh < 2; ++kh) {
            short8 af[8];
#pragma unroll
            for (int m = 0; m < 8; ++m)
                af[m] = *(const short8*)(B + swz(wr * 128 + m * 16 + lcol, kh * 4 + q));
#pragma unroll
            for (int m = 0; m < 8; ++m)
#pragma unroll
                for (int n = 0; n < 4; ++n)
                    acc[m][n] = __builtin_amdgcn_mfma_f32_16x16x32_bf16(
                        af[m], wv[kh * 4 + n], acc[m][n], 0, 0, 0);
        }
    };

    // ---- prologue: W(0) -> wv; gelu tiles 0,1 -> buf0,buf1 ----
    w_load(0);
    gelu_stage(0, lds);
    gelu_stage(1, lds + A_BYTES);
    asm volatile("s_waitcnt lgkmcnt(0)\n\ts_barrier" ::: "memory");

    // ---- main loop: 2 K-tiles per barrier, 4-buffer ring ----
    for (int j = 0; j < NKT / 2; ++j) {
        const int ka = 2 * j, kb = ka + 1;
        unsigned char* Ba = lds + (ka & 3) * A_BYTES;
        unsigned char* Bb = lds + (kb & 3) * A_BYTES;
        unsigned char* Sa = lds + ((ka + 2) & 3) * A_BYTES;
        unsigned char* Sb = lds + ((ka + 3) & 3) * A_BYTES;
        const bool stg = (ka + 2 < NKT);
        const bool gA = (ka + 2 < 4), gB = (ka + 3 < 4);

        // xs prefetch for the two tiles staged this period
        float xsA[4], xsB[4];
        if (stg && !gA) {
            const int ibA = (ka + 2 - 4) * 8;
#pragma unroll
            for (int rep = 0; rep < 4; ++rep)
                xsA[rep] = X[(size_t)(row0 + srow + rep * 64) * 256 + ibA + scol];
        }
        if (stg && !gB) {
            const int ibB = (ka + 3 - 4) * 8;
#pragma unroll
            for (int rep = 0; rep < 4; ++rep)
                xsB[rep] = X[(size_t)(row0 + srow + rep * 64) * 256 + ibB + scol];
        }

        mfma_tile(Ba);                 // uses wv(ka)
        w_load(kb);                    // L2; covered by staging below
        if (stg) { if (gA) gelu_stage(ka + 2, Sa); else spline_stage(xsA, Sa); }
        mfma_tile(Bb);                 // uses wv(kb)
        if (ka + 2 < NKT) w_load(ka + 2);
        if (stg) { if (gB) gelu_stage(ka + 3, Sb); else spline_stage(xsB, Sb); }

        // one LDS-only barrier per 2 K-tiles (W/x reg-loads stay in flight)
        asm volatile("s_waitcnt lgkmcnt(0)\n\ts_barrier" ::: "memory");
    }

    // ---- fused LayerNorm + PReLU epilogue (verified R7) ----
    float* stats = (float*)lds;   // [256][8]: 4 col-partial sums, 4 col-partial sumsq
#pragma unroll
    for (int m = 0; m < 8; ++m) {
#pragma unroll
        for (int r = 0; r < 4; ++r) {
            float s = 0.f, s2 = 0.f;
#pragma unroll
            for (int n = 0; n < 4; ++n) { float v = acc[m][n][r]; s += v; s2 += v * v; }
#pragma unroll
            for (int msk = 1; msk < 16; msk <<= 1) {
                s  += __shfl_xor(s,  msk, 64);
                s2 += __shfl_xor(s2, msk, 64);
            }
            if ((lane & 15) == ((m * 4 + r) & 15)) {
                int row = wr * 128 + m * 16 + q * 4 + r;
                stats[row * 8 + wc]     = s;
                stats[row * 8 + 4 + wc] = s2;
            }
        }
    }
    __syncthreads();

    const float apr = prelu_a[0];
    float gv[4], bv[4];
#pragma unroll
    for (int n = 0; n < 4; ++n) {
        int col = wc * 64 + n * 16 + lcol;
        gv[n] = gamma[col]; bv[n] = beta[col];
    }
#pragma unroll
    for (int m = 0; m < 8; ++m) {
#pragma unroll
        for (int r = 0; r < 4; ++r) {
            int row = wr * 128 + m * 16 + q * 4 + r;
            f32x4 sv = *(const f32x4*)(stats + row * 8);
            f32x4 qv = *(const f32x4*)(stats + row * 8 + 4);
            float mu  = (sv[0] + sv[1] + sv[2] + sv[3]) * (1.0f / 256.0f);
            float ex2 = (qv[0] + qv[1] + qv[2] + qv[3]) * (1.0f / 256.0f);
            float rs = rsqrtf(ex2 - mu * mu + 1e-5f);
            float* op = OUT + (size_t)(row0 + row) * 256;
#pragma unroll
            for (int n = 0; n < 4; ++n) {
                int col = wc * 64 + n * 16 + lcol;
                float y = (acc[m][n][r] - mu) * rs * gv[n] + bv[n];
                op[col] = (y >= 0.f) ? y : apr * y;
            }
        }
    }
}

extern "C" void kernel_launch(void* const* d_in, const int* in_sizes, int n_in,
                              void* d_out, int out_size, void* d_ws, size_t ws_size,
                              hipStream_t stream) {
    const float* x  = (const float*)d_in[0];
    // d_in[1] = grid knots (uniform linspace; constants folded into closed form)
    const float* bw = (const float*)d_in[2];
    const float* sw = (const float*)d_in[3];
    const float* g  = (const float*)d_in[4];
    const float* be = (const float*)d_in[5];
    const float* pa = (const float*)d_in[6];
    float* out = (float*)d_out;
    unsigned short* Wf = (unsigned short*)d_ws;   // 36*2048*16B frag-major

    hipFuncSetAttribute((const void*)kan_fused,
                        hipFuncAttributeMaxDynamicSharedMemorySize, LDS_TOTAL);

    const int Nrows = in_sizes[0] / 256;
    kan_prep_w<<<(NKT * 2048 + 255) / 256, 256, 0, stream>>>(bw, sw, Wf);
    kan_fused<<<Nrows / BM, 512, LDS_TOTAL, stream>>>(x, Wf, g, be, pa, out);
}